// Round 2
// baseline (288.730 us; speedup 1.0000x reference)
//
#include <hip/hip_runtime.h>
#include <math.h>

#define BLOCK 256

__device__ __forceinline__ float frcp(float x) { return __builtin_amdgcn_rcpf(x); }
__device__ __forceinline__ float frsq(float x) { return __builtin_amdgcn_rsqf(x); }

// Exact symmetric-Schur Jacobi rotation (Golub & Van Loan).
// Returns (c,s,t) zeroing off-diagonal apq of [[app,apq],[apq,aqq]].
__device__ __forceinline__ void jacobi_cs(float app, float apq, float aqq,
                                          float& c, float& s, float& t) {
    float tau = (aqq - app) * 0.5f * frcp(apq);       // inf/NaN if apq==0 -> guarded
    float tt  = copysignf(1.0f, tau) * frcp(fabsf(tau) + sqrtf(fmaf(tau, tau, 1.0f)));
    bool z = (apq == 0.0f);
    t = z ? 0.0f : tt;
    c = frsq(fmaf(t, t, 1.0f));
    s = t * c;
}

// Exact Givens for QR: zero y against x; new x = sqrt(x^2+y^2) >= 0.
__device__ __forceinline__ void qr_givens(float x, float y, float& c, float& s) {
    float d = fmaf(x, x, y * y);
    bool ok = d > 1e-30f;
    float inv = frsq(fmaxf(d, 1e-30f));
    c = ok ? x * inv : 1.0f;
    s = ok ? y * inv : 0.0f;
}

__global__ __launch_bounds__(BLOCK) void dp_kernel(
    const float* __restrict__ F,
    const float* __restrict__ p_yml,
    const float* __restrict__ p_nu,
    const float* __restrict__ p_fa,
    const float* __restrict__ p_coh,
    float* __restrict__ out,
    int n_elem)
{
    __shared__ float lds[BLOCK * 9];
    const int t_id = threadIdx.x;
    const long long base_f = (long long)blockIdx.x * (BLOCK * 9);
    const long long nfloats = (long long)n_elem * 9LL;

    // ---- stage in: coalesced float4 ----
    #pragma unroll
    for (int j = 0; j < 3; ++j) {
        int idx = t_id + j * BLOCK;
        if (idx < (BLOCK * 9) / 4) {
            long long g4 = base_f / 4 + idx;
            long long gf = g4 * 4;
            if (gf + 3 < nfloats) {
                ((float4*)lds)[idx] = ((const float4*)F)[g4];
            } else {
                #pragma unroll
                for (int k = 0; k < 4; ++k)
                    if (gf + k < nfloats) lds[idx * 4 + k] = F[gf + k];
            }
        }
    }
    __syncthreads();

    const long long e = (long long)blockIdx.x * BLOCK + t_id;
    const bool valid = e < n_elem;

    float a00, a01, a02, a10, a11, a12, a20, a21, a22;
    {
        const float* p = lds + t_id * 9;   // stride 9: 2-way bank alias only (free)
        a00 = p[0]; a01 = p[1]; a02 = p[2];
        a10 = p[3]; a11 = p[4]; a12 = p[5];
        a20 = p[6]; a21 = p[7]; a22 = p[8];
    }
    __syncthreads();

    // ---- material params ----
    const float yml = p_yml[0];
    const float nu  = p_nu[0];
    const float fa  = p_fa[0];
    const float coh = p_coh[0];
    const float E     = expf(yml);
    const float sphi  = sinf(fa * 0.017453292519943295f);
    const float alpha = 0.816496580927726f * 2.0f * sphi / (3.0f - sphi);
    const float mu    = E / (2.0f * (1.0f + nu));
    const float la    = E * nu / ((1.0f + nu) * (1.0f - 2.0f * nu));
    const float ratio = (3.0f * la + 2.0f * mu) / (2.0f * mu) * alpha;

    // ---- S = A^T A ----
    float s00 = a00*a00 + a10*a10 + a20*a20;
    float s01 = a00*a01 + a10*a11 + a20*a21;
    float s02 = a00*a02 + a10*a12 + a20*a22;
    float s11 = a01*a01 + a11*a11 + a21*a21;
    float s12 = a01*a02 + a11*a12 + a21*a22;
    float s22 = a02*a02 + a12*a12 + a22*a22;

    // ---- exact cyclic Jacobi, 4 sweeps; V accumulated ----
    float v00=1.f,v01=0.f,v02=0.f, v10=0.f,v11=1.f,v12=0.f, v20=0.f,v21=0.f,v22=1.f;
    float c, s, tj, t0, t1;
    #pragma unroll
    for (int sweep = 0; sweep < 4; ++sweep) {
        // (p,q) = (0,1)
        jacobi_cs(s00, s01, s11, c, s, tj);
        s00 = s00 - tj * s01;  s11 = s11 + tj * s01;  s01 = 0.0f;
        t0 = s02; t1 = s12;  s02 = c*t0 - s*t1;  s12 = s*t0 + c*t1;
        t0=v00; t1=v01; v00=c*t0-s*t1; v01=s*t0+c*t1;
        t0=v10; t1=v11; v10=c*t0-s*t1; v11=s*t0+c*t1;
        t0=v20; t1=v21; v20=c*t0-s*t1; v21=s*t0+c*t1;
        // (p,q) = (0,2)
        jacobi_cs(s00, s02, s22, c, s, tj);
        s00 = s00 - tj * s02;  s22 = s22 + tj * s02;  s02 = 0.0f;
        t0 = s01; t1 = s12;  s01 = c*t0 - s*t1;  s12 = s*t0 + c*t1;
        t0=v00; t1=v02; v00=c*t0-s*t1; v02=s*t0+c*t1;
        t0=v10; t1=v12; v10=c*t0-s*t1; v12=s*t0+c*t1;
        t0=v20; t1=v22; v20=c*t0-s*t1; v22=s*t0+c*t1;
        // (p,q) = (1,2)
        jacobi_cs(s11, s12, s22, c, s, tj);
        s11 = s11 - tj * s12;  s22 = s22 + tj * s12;  s12 = 0.0f;
        t0 = s01; t1 = s02;  s01 = c*t0 - s*t1;  s02 = s*t0 + c*t1;
        t0=v01; t1=v02; v01=c*t0-s*t1; v02=s*t0+c*t1;
        t0=v11; t1=v12; v11=c*t0-s*t1; v12=s*t0+c*t1;
        t0=v21; t1=v22; v21=c*t0-s*t1; v22=s*t0+c*t1;
    }

    // ---- sort eigenvalues descending; permute V columns ----
    {
        float tmp; bool sw;
        sw = s00 < s11;
        if (sw) { tmp=s00;s00=s11;s11=tmp; tmp=v00;v00=v01;v01=tmp;
                  tmp=v10;v10=v11;v11=tmp; tmp=v20;v20=v21;v21=tmp; }
        sw = s00 < s22;
        if (sw) { tmp=s00;s00=s22;s22=tmp; tmp=v00;v00=v02;v02=tmp;
                  tmp=v10;v10=v12;v12=tmp; tmp=v20;v20=v22;v22=tmp; }
        sw = s11 < s22;
        if (sw) { tmp=s11;s11=s22;s22=tmp; tmp=v01;v01=v02;v02=tmp;
                  tmp=v11;v11=v12;v12=tmp; tmp=v21;v21=v22;v22=tmp; }
    }

    // ---- B = A * V ----
    float b00 = a00*v00 + a01*v10 + a02*v20;
    float b01 = a00*v01 + a01*v11 + a02*v21;
    float b02 = a00*v02 + a01*v12 + a02*v22;
    float b10 = a10*v00 + a11*v10 + a12*v20;
    float b11 = a10*v01 + a11*v11 + a12*v21;
    float b12 = a10*v02 + a11*v12 + a12*v22;
    float b20 = a20*v00 + a21*v10 + a22*v20;
    float b21 = a20*v01 + a21*v11 + a22*v21;
    float b22 = a20*v02 + a21*v12 + a22*v22;

    // ---- Givens QR of B ----
    float u00=1.f,u01=0.f,u02=0.f, u10=0.f,u11=1.f,u12=0.f, u20=0.f,u21=0.f,u22=1.f;

    qr_givens(b00, b10, c, s);                       // zero b10
    t0=b00; b00=c*t0+s*b10;
    t0=b01; b01=c*t0+s*b11; b11=c*b11-s*t0;
    t0=b02; b02=c*t0+s*b12; b12=c*b12-s*t0;
    t0=u00; u00=c*t0+s*u01; u01=c*u01-s*t0;
    t0=u10; u10=c*t0+s*u11; u11=c*u11-s*t0;
    t0=u20; u20=c*t0+s*u21; u21=c*u21-s*t0;

    qr_givens(b00, b20, c, s);                       // zero b20
    t0=b00; b00=c*t0+s*b20;
    t0=b01; b01=c*t0+s*b21; b21=c*b21-s*t0;
    t0=b02; b02=c*t0+s*b22; b22=c*b22-s*t0;
    t0=u00; u00=c*t0+s*u02; u02=c*u02-s*t0;
    t0=u10; u10=c*t0+s*u12; u12=c*u12-s*t0;
    t0=u20; u20=c*t0+s*u22; u22=c*u22-s*t0;

    qr_givens(b11, b21, c, s);                       // zero b21
    t0=b11; b11=c*t0+s*b21;
    t0=b12; b12=c*t0+s*b22; b22=c*b22-s*t0;
    t0=u01; u01=c*t0+s*u02; u02=c*u02-s*t0;
    t0=u11; u11=c*t0+s*u12; u12=c*u12-s*t0;
    t0=u21; u21=c*t0+s*u22; u22=c*u22-s*t0;

    // sigma2 >= 0: fold sign into U column 2
    float sgn = b22 < 0.0f ? -1.0f : 1.0f;
    float sg2 = b22 * sgn;
    u02 *= sgn; u12 *= sgn; u22 *= sgn;

    // ---- Drucker-Prager return mapping ----
    float sig0 = fmaxf(b00, 0.05f);
    float sig1 = fmaxf(b11, 0.05f);
    float sig2 = fmaxf(sg2, 0.05f);
    float e0 = logf(sig0), e1 = logf(sig1), e2 = logf(sig2);
    float tr  = e0 + e1 + e2;
    float tr3 = tr * (1.0f / 3.0f);
    float h0 = e0 - tr3, h1 = e1 - tr3, h2 = e2 - tr3;
    float hn = sqrtf(h0*h0 + h1*h1 + h2*h2);
    hn = fmaxf(hn, 1e-10f);
    float st = tr - coh * 3.0f;
    float dg = hn + ratio * st;
    float sc = fmaxf(dg, 0.0f) * frcp(hn);
    bool yield = st < 0.0f;
    float ec0 = yield ? (e0 - sc * h0) : coh;
    float ec1 = yield ? (e1 - sc * h1) : coh;
    float ec2 = yield ? (e2 - sc * h2) : coh;
    float f0 = expf(ec0), f1 = expf(ec1), f2 = expf(ec2);

    // ---- F_corrected = U * diag(f) * V^T ----
    float w00=u00*f0, w01=u01*f1, w02=u02*f2;
    float w10=u10*f0, w11=u11*f1, w12=u12*f2;
    float w20=u20*f0, w21=u21*f1, w22=u22*f2;
    float r00 = w00*v00 + w01*v01 + w02*v02;
    float r01 = w00*v10 + w01*v11 + w02*v12;
    float r02 = w00*v20 + w01*v21 + w02*v22;
    float r10 = w10*v00 + w11*v01 + w12*v02;
    float r11 = w10*v10 + w11*v11 + w12*v12;
    float r12 = w10*v20 + w11*v21 + w12*v22;
    float r20 = w20*v00 + w21*v01 + w22*v02;
    float r21 = w20*v10 + w21*v11 + w22*v12;
    float r22 = w20*v20 + w21*v21 + w22*v22;

    // ---- stage out through LDS, coalesced ----
    if (valid) {
        float* p = lds + t_id * 9;
        p[0]=r00; p[1]=r01; p[2]=r02;
        p[3]=r10; p[4]=r11; p[5]=r12;
        p[6]=r20; p[7]=r21; p[8]=r22;
    }
    __syncthreads();

    #pragma unroll
    for (int j = 0; j < 3; ++j) {
        int idx = t_id + j * BLOCK;
        if (idx < (BLOCK * 9) / 4) {
            long long g4 = base_f / 4 + idx;
            long long gf = g4 * 4;
            if (gf + 3 < nfloats) {
                ((float4*)out)[g4] = ((float4*)lds)[idx];
            } else {
                #pragma unroll
                for (int k = 0; k < 4; ++k)
                    if (gf + k < nfloats) out[gf + k] = lds[idx * 4 + k];
            }
        }
    }
}

extern "C" void kernel_launch(void* const* d_in, const int* in_sizes, int n_in,
                              void* d_out, int out_size, void* d_ws, size_t ws_size,
                              hipStream_t stream) {
    const float* F = (const float*)d_in[0];
    const int n_elem = in_sizes[0] / 9;
    const int grid = (n_elem + BLOCK - 1) / BLOCK;
    dp_kernel<<<grid, BLOCK, 0, stream>>>(
        F,
        (const float*)d_in[1], (const float*)d_in[2],
        (const float*)d_in[3], (const float*)d_in[4],
        (float*)d_out, n_elem);
}

// Round 3
// 274.994 us; speedup vs baseline: 1.0499x; 1.0499x over previous
//
#include <hip/hip_runtime.h>
#include <math.h>

#define BLOCK 256

__device__ __forceinline__ float frcp(float x) { return __builtin_amdgcn_rcpf(x); }
__device__ __forceinline__ float frsq(float x) { return __builtin_amdgcn_rsqf(x); }

// One-sided (Hestenes) Jacobi rotation on columns (x,y) of A and (p,q) of V.
// Orthogonalizes the column pair; de Rijk variant keeps norm(col_p) >= norm(col_q).
// 2 transcendentals (sqrt + rsqrt) per rotation.
__device__ __forceinline__ void onesided_rot(
    float& x0, float& x1, float& x2,
    float& y0, float& y1, float& y2,
    float& p0, float& p1, float& p2,
    float& q0, float& q1, float& q2)
{
    float app = fmaf(x0, x0, fmaf(x1, x1, x2 * x2));
    float aqq = fmaf(y0, y0, fmaf(y1, y1, y2 * y2));
    float apq = fmaf(x0, y0, fmaf(x1, y1, x2 * y2));
    float del = app - aqq;
    float rho = apq + apq;
    float r   = sqrtf(fmaf(del, del, rho * rho));
    // small-angle root: tan(theta) = sgn(del)*rho / (|del| + r)
    float ch = fabsf(del) + r;
    float sh = (del < 0.0f) ? -rho : rho;
    float n2 = fmaf(ch, ch, sh * sh);
    float inv = frsq(n2);
    bool ok = n2 > 1e-30f;
    float c = ok ? ch * inv : 1.0f;
    float s = ok ? sh * inv : 0.0f;
    // de Rijk ordering: if app < aqq, use theta+90deg -> columns swap (with sign)
    bool sw = del < 0.0f;
    float cf = sw ? -s : c;
    float sf = sw ?  c : s;
    float t;
    t = x0; x0 = fmaf(cf, t, sf * y0); y0 = fmaf(cf, y0, -sf * t);
    t = x1; x1 = fmaf(cf, t, sf * y1); y1 = fmaf(cf, y1, -sf * t);
    t = x2; x2 = fmaf(cf, t, sf * y2); y2 = fmaf(cf, y2, -sf * t);
    t = p0; p0 = fmaf(cf, t, sf * q0); q0 = fmaf(cf, q0, -sf * t);
    t = p1; p1 = fmaf(cf, t, sf * q1); q1 = fmaf(cf, q1, -sf * t);
    t = p2; p2 = fmaf(cf, t, sf * q2); q2 = fmaf(cf, q2, -sf * t);
}

__global__ __launch_bounds__(BLOCK) void dp_kernel(
    const float* __restrict__ F,
    const float* __restrict__ p_yml,
    const float* __restrict__ p_nu,
    const float* __restrict__ p_fa,
    const float* __restrict__ p_coh,
    float* __restrict__ out,
    int n_elem)
{
    __shared__ float lds[BLOCK * 9];
    const int t_id = threadIdx.x;
    const long long base_f = (long long)blockIdx.x * (BLOCK * 9);
    const long long nfloats = (long long)n_elem * 9LL;

    // ---- stage in: coalesced float4 ----
    #pragma unroll
    for (int j = 0; j < 3; ++j) {
        int idx = t_id + j * BLOCK;
        if (idx < (BLOCK * 9) / 4) {
            long long g4 = base_f / 4 + idx;
            long long gf = g4 * 4;
            if (gf + 3 < nfloats) {
                ((float4*)lds)[idx] = ((const float4*)F)[g4];
            } else {
                #pragma unroll
                for (int k = 0; k < 4; ++k)
                    if (gf + k < nfloats) lds[idx * 4 + k] = F[gf + k];
            }
        }
    }
    __syncthreads();

    const long long e = (long long)blockIdx.x * BLOCK + t_id;
    const bool valid = e < n_elem;

    // A by columns: aRC = row R, col C
    float a00, a01, a02, a10, a11, a12, a20, a21, a22;
    {
        const float* p = lds + t_id * 9;   // stride 9: 2-way bank alias only (free)
        a00 = p[0]; a01 = p[1]; a02 = p[2];
        a10 = p[3]; a11 = p[4]; a12 = p[5];
        a20 = p[6]; a21 = p[7]; a22 = p[8];
    }
    __syncthreads();

    // ---- material params ----
    const float yml = p_yml[0];
    const float nu  = p_nu[0];
    const float fa  = p_fa[0];
    const float coh = p_coh[0];
    const float E     = __expf(yml);
    const float sphi  = __sinf(fa * 0.017453292519943295f);
    const float alpha = 1.632993161855452f * sphi * frcp(3.0f - sphi); // sqrt(2/3)*2*sin/(3-sin)
    const float mu    = E * 0.5f * frcp(1.0f + nu);
    const float la    = E * nu * frcp((1.0f + nu) * (1.0f - 2.0f * nu));
    const float ratio = (3.0f * la + 2.0f * mu) * frcp(2.0f * mu) * alpha;

    // ---- one-sided Jacobi: A <- A*G, V <- V*G; columns of A -> sigma_i * u_i ----
    float v00=1.f,v01=0.f,v02=0.f, v10=0.f,v11=1.f,v12=0.f, v20=0.f,v21=0.f,v22=1.f;
    #pragma unroll
    for (int sweep = 0; sweep < 4; ++sweep) {
        onesided_rot(a00,a10,a20, a01,a11,a21, v00,v10,v20, v01,v11,v21); // (0,1)
        onesided_rot(a00,a10,a20, a02,a12,a22, v00,v10,v20, v02,v12,v22); // (0,2)
        onesided_rot(a01,a11,a21, a02,a12,a22, v01,v11,v21, v02,v12,v22); // (1,2)
    }

    // ---- recover U, sigma (descending by de Rijk ordering) ----
    float n0sq = fmaf(a00,a00, fmaf(a10,a10, a20*a20));
    float n1sq = fmaf(a01,a01, fmaf(a11,a11, a21*a21));
    float i0 = frsq(fmaxf(n0sq, 1e-30f));
    float i1 = frsq(fmaxf(n1sq, 1e-30f));
    float u00 = a00*i0, u10 = a10*i0, u20 = a20*i0;
    float u01 = a01*i1, u11 = a11*i1, u21 = a21*i1;
    float sig0 = n0sq * i0;
    float sig1 = n1sq * i1;
    // u2 = u0 x u1 (orthonormal by construction); sigma2 & sign from <u2, a_col2>
    float u02 = fmaf(u10, u21, -u20*u11);
    float u12 = fmaf(u20, u01, -u00*u21);
    float u22 = fmaf(u00, u11, -u10*u01);
    float d3  = fmaf(u02, a02, fmaf(u12, a12, u22*a22));
    float sig2 = fabsf(d3);

    // ---- Drucker-Prager return mapping on log strains ----
    float e0 = __logf(fmaxf(sig0, 0.05f));
    float e1 = __logf(fmaxf(sig1, 0.05f));
    float e2 = __logf(fmaxf(sig2, 0.05f));
    float tr  = e0 + e1 + e2;
    float tr3 = tr * (1.0f / 3.0f);
    float h0 = e0 - tr3, h1 = e1 - tr3, h2 = e2 - tr3;
    float hn = sqrtf(fmaf(h0,h0, fmaf(h1,h1, h2*h2)));
    hn = fmaxf(hn, 1e-10f);
    float st = tr - coh * 3.0f;
    float dg = hn + ratio * st;
    float sc = fmaxf(dg, 0.0f) * frcp(hn);
    bool yield = st < 0.0f;
    float ec0 = yield ? fmaf(-sc, h0, e0) : coh;
    float ec1 = yield ? fmaf(-sc, h1, e1) : coh;
    float ec2 = yield ? fmaf(-sc, h2, e2) : coh;
    float f0 = __expf(ec0);
    float f1 = __expf(ec1);
    float f2 = copysignf(__expf(ec2), d3);   // fold u2-sign into the scale

    // ---- F_corrected = sum_k f_k * u_k * v_k^T ----
    float w00 = u00*f0, w01 = u01*f1, w02 = u02*f2;
    float w10 = u10*f0, w11 = u11*f1, w12 = u12*f2;
    float w20 = u20*f0, w21 = u21*f1, w22 = u22*f2;
    float r00 = fmaf(w00,v00, fmaf(w01,v01, w02*v02));
    float r01 = fmaf(w00,v10, fmaf(w01,v11, w02*v12));
    float r02 = fmaf(w00,v20, fmaf(w01,v21, w02*v22));
    float r10 = fmaf(w10,v00, fmaf(w11,v01, w12*v02));
    float r11 = fmaf(w10,v10, fmaf(w11,v11, w12*v12));
    float r12 = fmaf(w10,v20, fmaf(w11,v21, w12*v22));
    float r20 = fmaf(w20,v00, fmaf(w21,v01, w22*v02));
    float r21 = fmaf(w20,v10, fmaf(w21,v11, w22*v12));
    float r22 = fmaf(w20,v20, fmaf(w21,v21, w22*v22));

    // ---- stage out through LDS, coalesced ----
    if (valid) {
        float* p = lds + t_id * 9;
        p[0]=r00; p[1]=r01; p[2]=r02;
        p[3]=r10; p[4]=r11; p[5]=r12;
        p[6]=r20; p[7]=r21; p[8]=r22;
    }
    __syncthreads();

    #pragma unroll
    for (int j = 0; j < 3; ++j) {
        int idx = t_id + j * BLOCK;
        if (idx < (BLOCK * 9) / 4) {
            long long g4 = base_f / 4 + idx;
            long long gf = g4 * 4;
            if (gf + 3 < nfloats) {
                ((float4*)out)[g4] = ((float4*)lds)[idx];
            } else {
                #pragma unroll
                for (int k = 0; k < 4; ++k)
                    if (gf + k < nfloats) out[gf + k] = lds[idx * 4 + k];
            }
        }
    }
}

extern "C" void kernel_launch(void* const* d_in, const int* in_sizes, int n_in,
                              void* d_out, int out_size, void* d_ws, size_t ws_size,
                              hipStream_t stream) {
    const float* F = (const float*)d_in[0];
    const int n_elem = in_sizes[0] / 9;
    const int grid = (n_elem + BLOCK - 1) / BLOCK;
    dp_kernel<<<grid, BLOCK, 0, stream>>>(
        F,
        (const float*)d_in[1], (const float*)d_in[2],
        (const float*)d_in[3], (const float*)d_in[4],
        (float*)d_out, n_elem);
}

// Round 4
// 269.990 us; speedup vs baseline: 1.0694x; 1.0185x over previous
//
#include <hip/hip_runtime.h>
#include <math.h>

#define BLOCK 256

__device__ __forceinline__ float frcp(float x) { return __builtin_amdgcn_rcpf(x); }
__device__ __forceinline__ float frsq(float x) { return __builtin_amdgcn_rsqf(x); }

// One-sided (Hestenes) Jacobi rotation on columns (p,q) of A only (no V).
// Squared column norms np, nq carried and updated analytically:
// after an exact rotation the pair Gram is diag(((np+nq)+r)/2, ((np+nq)-r)/2).
// de Rijk variant keeps np >= nq (descending order for free).
__device__ __forceinline__ void rot(
    float& x0, float& x1, float& x2, float& np,
    float& y0, float& y1, float& y2, float& nq)
{
    float apq = fmaf(x0, y0, fmaf(x1, y1, x2 * y2));
    float del = np - nq;
    float rho = apq + apq;
    float r   = sqrtf(fmaf(del, del, rho * rho));
    float ch  = fabsf(del) + r;                 // unnormalized cos
    float sh  = (del < 0.0f) ? -rho : rho;      // unnormalized sin
    float nn  = fmaf(ch, ch, sh * sh);
    float inv = frsq(nn);
    bool ok = nn > 1e-30f;
    float c = ok ? ch * inv : 1.0f;
    float s = ok ? sh * inv : 0.0f;
    bool sw = del < 0.0f;                       // de Rijk: rotate by theta+90deg
    float cf = sw ? -s : c;
    float sf = sw ?  c : s;
    float t;
    t = x0; x0 = fmaf(cf, t, sf * y0); y0 = fmaf(cf, y0, -sf * t);
    t = x1; x1 = fmaf(cf, t, sf * y1); y1 = fmaf(cf, y1, -sf * t);
    t = x2; x2 = fmaf(cf, t, sf * y2); y2 = fmaf(cf, y2, -sf * t);
    float sum = np + nq;
    np = 0.5f * (sum + r);
    nq = fmaxf(0.5f * (sum - r), 0.0f);
}

__global__ __launch_bounds__(BLOCK) void dp_kernel(
    const float* __restrict__ F,
    const float* __restrict__ p_yml,
    const float* __restrict__ p_nu,
    const float* __restrict__ p_fa,
    const float* __restrict__ p_coh,
    float* __restrict__ out,
    int n_elem)
{
    __shared__ float lds[BLOCK * 9];
    const int t_id = threadIdx.x;
    const long long base_f = (long long)blockIdx.x * (BLOCK * 9);
    const long long nfloats = (long long)n_elem * 9LL;

    // ---- stage in: coalesced float4 ----
    #pragma unroll
    for (int j = 0; j < 3; ++j) {
        int idx = t_id + j * BLOCK;
        if (idx < (BLOCK * 9) / 4) {
            long long g4 = base_f / 4 + idx;
            long long gf = g4 * 4;
            if (gf + 3 < nfloats) {
                ((float4*)lds)[idx] = ((const float4*)F)[g4];
            } else {
                #pragma unroll
                for (int k = 0; k < 4; ++k)
                    if (gf + k < nfloats) lds[idx * 4 + k] = F[gf + k];
            }
        }
    }
    __syncthreads();

    const long long e = (long long)blockIdx.x * BLOCK + t_id;
    const bool valid = e < n_elem;

    // original A (kept for V recovery): aRC = row R, col C
    float a00, a01, a02, a10, a11, a12, a20, a21, a22;
    {
        const float* p = lds + t_id * 9;   // stride 9: 2-way bank alias only (free)
        a00 = p[0]; a01 = p[1]; a02 = p[2];
        a10 = p[3]; a11 = p[4]; a12 = p[5];
        a20 = p[6]; a21 = p[7]; a22 = p[8];
    }
    __syncthreads();

    // ---- material params ----
    const float yml = p_yml[0];
    const float nu  = p_nu[0];
    const float fa  = p_fa[0];
    const float coh = p_coh[0];
    const float E     = __expf(yml);
    const float sphi  = __sinf(fa * 0.017453292519943295f);
    const float alpha = 1.632993161855452f * sphi * frcp(3.0f - sphi);
    const float mu    = E * 0.5f * frcp(1.0f + nu);
    const float la    = E * nu * frcp((1.0f + nu) * (1.0f - 2.0f * nu));
    const float ratio = (3.0f * la + 2.0f * mu) * frcp(2.0f * mu) * alpha;

    // ---- working copy of A's columns + squared norms ----
    float c00=a00, c10=a10, c20=a20;   // col 0
    float c01=a01, c11=a11, c21=a21;   // col 1
    float c02=a02, c12=a12, c22=a22;   // col 2
    float n0 = fmaf(c00,c00, fmaf(c10,c10, c20*c20));
    float n1 = fmaf(c01,c01, fmaf(c11,c11, c21*c21));
    float n2 = fmaf(c02,c02, fmaf(c12,c12, c22*c22));

    // ---- one-sided Jacobi, 4 cyclic sweeps (no V accumulation) ----
    #pragma unroll
    for (int sweep = 0; sweep < 4; ++sweep) {
        rot(c00,c10,c20,n0, c01,c11,c21,n1);   // (0,1)
        rot(c00,c10,c20,n0, c02,c12,c22,n2);   // (0,2)
        rot(c01,c11,c21,n1, c02,c12,c22,n2);   // (1,2)
    }

    // ---- U and sigma (descending by de Rijk) ----
    float i0 = frsq(fmaxf(n0, 1e-30f));
    float i1 = frsq(fmaxf(n1, 1e-30f));
    float u00 = c00*i0, u10 = c10*i0, u20 = c20*i0;
    float u01 = c01*i1, u11 = c11*i1, u21 = c21*i1;
    float sig0 = n0 * i0;                      // sqrt(n0)
    float sig1 = n1 * i1;
    float u02 = fmaf(u10,u21, -u20*u11);       // u2 = u0 x u1
    float u12 = fmaf(u20,u01, -u00*u21);
    float u22 = fmaf(u00,u11, -u10*u01);

    // ---- V recovery: v_i = normalize(A^T u_i), v2 = v0 x v1 ----
    float q0 = fmaf(a00,u00, fmaf(a10,u10, a20*u20));   // (A^T u0)
    float q1 = fmaf(a01,u00, fmaf(a11,u10, a21*u20));
    float q2 = fmaf(a02,u00, fmaf(a12,u10, a22*u20));
    float m0 = fmaf(q0,q0, fmaf(q1,q1, q2*q2));
    float j0 = frsq(fmaxf(m0, 1e-30f));
    float v00 = q0*j0, v10 = q1*j0, v20 = q2*j0;

    q0 = fmaf(a00,u01, fmaf(a10,u11, a20*u21));         // (A^T u1)
    q1 = fmaf(a01,u01, fmaf(a11,u11, a21*u21));
    q2 = fmaf(a02,u01, fmaf(a12,u11, a22*u21));
    float m1 = fmaf(q0,q0, fmaf(q1,q1, q2*q2));
    float j1 = frsq(fmaxf(m1, 1e-30f));
    float v01 = q0*j1, v11 = q1*j1, v21 = q2*j1;

    float v02 = fmaf(v10,v21, -v20*v11);                // v2 = v0 x v1
    float v12 = fmaf(v20,v01, -v00*v21);
    float v22 = fmaf(v00,v11, -v10*v01);

    // third singular term coefficient (signed): s2 = u2^T A v2
    float w0 = fmaf(a00,v02, fmaf(a01,v12, a02*v22));
    float w1 = fmaf(a10,v02, fmaf(a11,v12, a12*v22));
    float w2 = fmaf(a20,v02, fmaf(a21,v12, a22*v22));
    float s2 = fmaf(u02,w0, fmaf(u12,w1, u22*w2));
    float sig2 = fabsf(s2);

    // ---- Drucker-Prager return mapping on log strains ----
    float e0 = __logf(fmaxf(sig0, 0.05f));
    float e1 = __logf(fmaxf(sig1, 0.05f));
    float e2 = __logf(fmaxf(sig2, 0.05f));
    float tr  = e0 + e1 + e2;
    float tr3 = tr * (1.0f / 3.0f);
    float h0 = e0 - tr3, h1 = e1 - tr3, h2 = e2 - tr3;
    float hn = sqrtf(fmaf(h0,h0, fmaf(h1,h1, h2*h2)));
    hn = fmaxf(hn, 1e-10f);
    float st = tr - coh * 3.0f;
    float dg = hn + ratio * st;
    float sc = fmaxf(dg, 0.0f) * frcp(hn);
    bool yield = st < 0.0f;
    float ec0 = yield ? fmaf(-sc, h0, e0) : coh;
    float ec1 = yield ? fmaf(-sc, h1, e1) : coh;
    float ec2 = yield ? fmaf(-sc, h2, e2) : coh;
    float f0 = __expf(ec0);
    float f1 = __expf(ec1);
    float f2 = copysignf(__expf(ec2), s2);     // fold third-term sign into scale

    // ---- F_corrected = sum_k f_k * u_k * v_k^T ----
    float w00 = u00*f0, w01 = u01*f1, w02 = u02*f2;
    float w10 = u10*f0, w11 = u11*f1, w12 = u12*f2;
    float w20 = u20*f0, w21 = u21*f1, w22 = u22*f2;
    float r00 = fmaf(w00,v00, fmaf(w01,v01, w02*v02));
    float r01 = fmaf(w00,v10, fmaf(w01,v11, w02*v12));
    float r02 = fmaf(w00,v20, fmaf(w01,v21, w02*v22));
    float r10 = fmaf(w10,v00, fmaf(w11,v01, w12*v02));
    float r11 = fmaf(w10,v10, fmaf(w11,v11, w12*v12));
    float r12 = fmaf(w10,v20, fmaf(w11,v21, w12*v22));
    float r20 = fmaf(w20,v00, fmaf(w21,v01, w22*v02));
    float r21 = fmaf(w20,v10, fmaf(w21,v11, w22*v12));
    float r22 = fmaf(w20,v20, fmaf(w21,v21, w22*v22));

    // ---- stage out through LDS, coalesced ----
    if (valid) {
        float* p = lds + t_id * 9;
        p[0]=r00; p[1]=r01; p[2]=r02;
        p[3]=r10; p[4]=r11; p[5]=r12;
        p[6]=r20; p[7]=r21; p[8]=r22;
    }
    __syncthreads();

    #pragma unroll
    for (int j = 0; j < 3; ++j) {
        int idx = t_id + j * BLOCK;
        if (idx < (BLOCK * 9) / 4) {
            long long g4 = base_f / 4 + idx;
            long long gf = g4 * 4;
            if (gf + 3 < nfloats) {
                ((float4*)out)[g4] = ((float4*)lds)[idx];
            } else {
                #pragma unroll
                for (int k = 0; k < 4; ++k)
                    if (gf + k < nfloats) out[gf + k] = lds[idx * 4 + k];
            }
        }
    }
}

extern "C" void kernel_launch(void* const* d_in, const int* in_sizes, int n_in,
                              void* d_out, int out_size, void* d_ws, size_t ws_size,
                              hipStream_t stream) {
    const float* F = (const float*)d_in[0];
    const int n_elem = in_sizes[0] / 9;
    const int grid = (n_elem + BLOCK - 1) / BLOCK;
    dp_kernel<<<grid, BLOCK, 0, stream>>>(
        F,
        (const float*)d_in[1], (const float*)d_in[2],
        (const float*)d_in[3], (const float*)d_in[4],
        (float*)d_out, n_elem);
}